// Round 9
// baseline (39.978 us; speedup 1.0000x reference)
//
#include <hip/hip_runtime.h>
#include <cstdint>

// Rule 30, 2 states, r=1, wrap. idx = L + 2C + 4R, table = bits of 30
// reduces to: new = R ^ (C | L).
//
// B=16 rows, W=2048 cells, T=1024 steps, history = T+1 states.
// Output: int32 [B][T+1][W] (reference returns uint8 -> harness int32).
//
// Round-9 = round-8 + CHAIN-WAVE SIMD SPREADING.
//   R8 post-mortem: 29.4 us with write stream done early -> tail is the
//   chain. All blocks used wave 0 for the chain; HW places wave 0 of every
//   block on SIMD 0, so the 4 co-resident blocks' chains time-shared ONE
//   SIMD at ~1/4 issue rate (1024 steps x ~18cy x 4 ~= 29 us = measured).
//   Fix: chain wave = (blk ^ (blk>>8)) & 3 -- distinct per co-resident
//   block under both chunked (blk&3 varies) and stride-256 ((blk>>8)&3
//   varies) block->CU assignments -> chains land on 4 different SIMDs.
//
// Structure otherwise identical to R8: 1024 blocks x 256 thr; chain wave
// re-runs row b's bit-packed chain from t=0 (ghost-zone window, 1 shuffle
// pair / 16 steps, win = (win>>1) ^ (win | (win<<1))), parks 16 states in
// LDS; barrier; all 4 waves expand 4 states each with NT int4 stores.

#define B 16
#define W 2048
#define T_ITERS 1024
#define HIST (T_ITERS + 1)
#define LANES 64
#define K_STEPS 16
#define RBLKS (T_ITERS / K_STEPS)      // 64 chunks
#define ROW_I4 (W / 4)                 // 512 int4 per state row

typedef unsigned long long u64;
typedef int v4i __attribute__((ext_vector_type(4)));

__device__ __forceinline__ void store_nib_nt(v4i* o, unsigned nib) {
    v4i f;
    f.x = (int)(nib & 1u);
    f.y = (int)((nib >> 1) & 1u);
    f.z = (int)((nib >> 2) & 1u);
    f.w = (int)((nib >> 3) & 1u);
    __builtin_nontemporal_store(f, o);   // global_store_dwordx4 ... nt
}

__global__ __launch_bounds__(256) void ca_redundant(const float* __restrict__ x,
                                                    v4i* __restrict__ out) {
    __shared__ unsigned st[K_STEPS][LANES];   // chunk's 16 packed states
    __shared__ unsigned st0[LANES];           // packed t=0 (r==0 only)

    const int blk = blockIdx.x;
    const int b = blk & (B - 1);              // row
    const int r = blk >> 4;                   // time-chunk 0..63
    const int tid = threadIdx.x;
    const int wave = tid >> 6;                // 0..3
    const int l = tid & 63;                   // lane
    const int cw = (blk ^ (blk >> 8)) & 3;    // chain wave: distinct per
                                              // co-resident block -> own SIMD

    if (wave == cw) {
        // ---- pack 32 thresholded floats into a u32 (bit i = cell 32l+i) ----
        const float4* xv = (const float4*)(x + (size_t)b * W + (size_t)l * 32);
        unsigned m = 0;
        #pragma unroll
        for (int i = 0; i < 8; ++i) {
            float4 v = xv[i];
            unsigned n = (v.x >= 0.5f ? 1u : 0u) | (v.y >= 0.5f ? 2u : 0u) |
                         (v.z >= 0.5f ? 4u : 0u) | (v.w >= 0.5f ? 8u : 0u);
            m |= n << (4 * i);
        }
        if (r == 0) st0[l] = m;

        // ---- chain: r+1 exchange groups of 16 steps; save only group r ----
        for (int g = 0; g <= r; ++g) {
            unsigned left  = __shfl(m, (l + LANES - 1) & (LANES - 1));
            unsigned right = __shfl(m, (l + 1) & (LANES - 1));
            // window bit p = cell (32l - 16 + p); bits [16..47] = own cells
            u64 win = ((u64)(left >> 16)) | ((u64)m << 16) | ((u64)right << 48);
            if (g < r) {
                #pragma unroll
                for (int j = 0; j < K_STEPS; ++j)
                    win = (win >> 1) ^ (win | (win << 1));   // rule 30, 64 bits
                m = (unsigned)(win >> 16);                   // valid at 16 steps
            } else {
                #pragma unroll
                for (int j = 0; j < K_STEPS; ++j) {
                    win = (win >> 1) ^ (win | (win << 1));
                    m = (unsigned)(win >> 16);               // valid for j<=15
                    st[j][l] = m;                            // 2 lanes/bank: free
                }
            }
        }
    }
    __syncthreads();

    // ---- expand: all 4 waves, 4 states each; contiguous NT int4 stores ----
    // nibble c of a packed row: word c>>3 = (l>>3)+8i, shift (l&7)*4.
    // LDS reads: 8-lane broadcast per word, 8 words across 8 banks -> clean.
    if (r == 0) {
        // t = 0 row: 512 int4 split across all 256 threads (2 each)
        v4i* o = out + ((size_t)b * HIST) * ROW_I4;
        #pragma unroll
        for (int h = 0; h < 2; ++h) {
            int c = tid + 256 * h;
            unsigned u = st0[c >> 3];
            store_nib_nt(o + c, (u >> ((c & 7) * 4)) & 0xFu);
        }
    }
    #pragma unroll
    for (int jj = 0; jj < 4; ++jj) {
        const int j = wave * 4 + jj;
        v4i* o = out + ((size_t)b * HIST + (size_t)(r * K_STEPS + 1 + j)) * ROW_I4;
        #pragma unroll
        for (int i = 0; i < 8; ++i) {
            unsigned u = st[j][(l >> 3) + 8 * i];
            store_nib_nt(o + l + 64 * i, (u >> ((l & 7) * 4)) & 0xFu);
        }
    }
}

extern "C" void kernel_launch(void* const* d_in, const int* in_sizes, int n_in,
                              void* d_out, int out_size, void* d_ws, size_t ws_size,
                              hipStream_t stream) {
    const float* x = (const float*)d_in[0];
    // 1024 independent blocks (4 waves each); no workspace needed.
    ca_redundant<<<B * RBLKS, 256, 0, stream>>>(x, (v4i*)d_out);
}

// Round 10
// 30.604 us; speedup vs baseline: 1.3063x; 1.3063x over previous
//
#include <hip/hip_runtime.h>
#include <cstdint>

// Rule 30, 2 states, r=1, wrap. idx = L + 2C + 4R, table = bits of 30
// reduces to: new = R ^ (C | L).
//
// B=16 rows, W=2048 cells, T=1024 steps, history = T+1 states.
// Output: int32 [B][T+1][W] (reference returns uint8 -> harness int32).
//
// Round-10: 1 block/CU + in-block chain/store PIPELINE.
//   R8 (29.4us): 1024 blocks, chain-then-store per block -> stores gated on
//   own chain; 4 chains/CU contend. R9 (spread chains): 40us, REFUTED
//   spreading; also killed issue-rate theories (1 wave-instr = 1KB stored;
//   issue is abundant). Remaining levers: decouple chain from store in
//   TIME (pipeline), give each chain a full SIMD (1 block/CU), and write
//   fewer/longer streams (256 x 524KB) matching the fill kernel's profile
//   (~3 pure-store waves/CU sustain 6.5-6.9 TB/s on this buffer).
//
//   Grid = 16 rows x 16 chunks(64 steps) = 256 blocks x 256 thr.
//   Block (b,q): head chain q*64 steps (wave 0, full SIMD rate, ghost-zone
//   window: 1 shuffle pair per 16 steps, win = (win>>1)^(win|(win<<1))),
//   then 4 pipelined sub-chunks: wave 0 computes sub-chunk s+1 into
//   st[(s+1)&1] while all 4 waves expand st[s&1] with NT int4 stores.
//   Double-buffer hazards covered by the per-iteration __syncthreads.

#define B 16
#define W 2048
#define T_ITERS 1024
#define HIST (T_ITERS + 1)
#define LANES 64
#define K_STEPS 16
#define SUBS 4                          // sub-chunks per block
#define QBLKS (T_ITERS / (K_STEPS * SUBS))   // 16 chunks of 64 steps
#define ROW_I4 (W / 4)                  // 512 int4 per state row

typedef unsigned long long u64;
typedef int v4i __attribute__((ext_vector_type(4)));

__device__ __forceinline__ void store_nib_nt(v4i* o, unsigned nib) {
    v4i f;
    f.x = (int)(nib & 1u);
    f.y = (int)((nib >> 1) & 1u);
    f.z = (int)((nib >> 2) & 1u);
    f.w = (int)((nib >> 3) & 1u);
    __builtin_nontemporal_store(f, o);   // global_store_dwordx4 ... nt
}

__global__ __launch_bounds__(256) void ca_pipe(const float* __restrict__ x,
                                               v4i* __restrict__ out) {
    __shared__ unsigned st[2][K_STEPS][LANES];   // double-buffered sub-chunk
    __shared__ unsigned st0[LANES];              // packed t=0 (q==0 only)

    const int blk = blockIdx.x;
    const int b = blk & (B - 1);          // row
    const int q = blk >> 4;               // 64-step chunk 0..15
    const int tid = threadIdx.x;
    const int wave = tid >> 6;            // 0..3
    const int l = tid & 63;               // lane

    unsigned m = 0;
    if (wave == 0) {
        // ---- pack 32 thresholded floats into u32 (bit i = cell 32l+i) ----
        const float4* xv = (const float4*)(x + (size_t)b * W + (size_t)l * 32);
        #pragma unroll
        for (int i = 0; i < 8; ++i) {
            float4 v = xv[i];
            unsigned n = (v.x >= 0.5f ? 1u : 0u) | (v.y >= 0.5f ? 2u : 0u) |
                         (v.z >= 0.5f ? 4u : 0u) | (v.w >= 0.5f ? 8u : 0u);
            m |= n << (4 * i);
        }
        if (q == 0) st0[l] = m;

        // ---- head chain: q*4 groups of 16 steps, no stores ----
        for (int g = 0; g < q * SUBS; ++g) {
            unsigned left  = __shfl(m, (l + LANES - 1) & (LANES - 1));
            unsigned right = __shfl(m, (l + 1) & (LANES - 1));
            u64 win = ((u64)(left >> 16)) | ((u64)m << 16) | ((u64)right << 48);
            #pragma unroll
            for (int j = 0; j < K_STEPS; ++j)
                win = (win >> 1) ^ (win | (win << 1));   // rule 30, 64 bits
            m = (unsigned)(win >> 16);                   // valid at 16 steps
        }
        // ---- sub-chunk 0 into buffer 0 ----
        {
            unsigned left  = __shfl(m, (l + LANES - 1) & (LANES - 1));
            unsigned right = __shfl(m, (l + 1) & (LANES - 1));
            u64 win = ((u64)(left >> 16)) | ((u64)m << 16) | ((u64)right << 48);
            #pragma unroll
            for (int j = 0; j < K_STEPS; ++j) {
                win = (win >> 1) ^ (win | (win << 1));
                m = (unsigned)(win >> 16);               // valid for j<=15
                st[0][j][l] = m;                         // 2 lanes/bank: free
            }
        }
    }
    __syncthreads();

    // ---- t=0 row (block q==0): 512 int4 across 256 threads ----
    if (q == 0) {
        v4i* o = out + ((size_t)b * HIST) * ROW_I4;
        #pragma unroll
        for (int h = 0; h < 2; ++h) {
            int c = tid + 256 * h;
            unsigned u = st0[c >> 3];
            store_nib_nt(o + c, (u >> ((c & 7) * 4)) & 0xFu);
        }
    }

    // ---- pipelined sub-chunks: compute s+1 (wave 0) || store s (all) ----
    for (int s = 0; s < SUBS; ++s) {
        if (wave == 0 && s < SUBS - 1) {
            unsigned left  = __shfl(m, (l + LANES - 1) & (LANES - 1));
            unsigned right = __shfl(m, (l + 1) & (LANES - 1));
            u64 win = ((u64)(left >> 16)) | ((u64)m << 16) | ((u64)right << 48);
            unsigned* dst = &st[(s + 1) & 1][0][l];
            #pragma unroll
            for (int j = 0; j < K_STEPS; ++j) {
                win = (win >> 1) ^ (win | (win << 1));
                m = (unsigned)(win >> 16);
                dst[j * LANES] = m;
            }
        }
        // store sub-chunk s: 16 states, 4 per wave; NT int4 wave-stores.
        // nibble c of a packed row: word c>>3 = (l>>3)+8i, shift (l&7)*4.
        const size_t t0 = (size_t)(q * (K_STEPS * SUBS) + s * K_STEPS + 1);
        #pragma unroll
        for (int jj = 0; jj < 4; ++jj) {
            const int j = wave * 4 + jj;
            v4i* o = out + ((size_t)b * HIST + t0 + j) * ROW_I4;
            #pragma unroll
            for (int i = 0; i < 8; ++i) {
                unsigned u = st[s & 1][j][(l >> 3) + 8 * i];
                store_nib_nt(o + l + 64 * i, (u >> ((l & 7) * 4)) & 0xFu);
            }
        }
        __syncthreads();   // readers done with st[s&1] before it's rewritten
    }
}

extern "C" void kernel_launch(void* const* d_in, const int* in_sizes, int n_in,
                              void* d_out, int out_size, void* d_ws, size_t ws_size,
                              hipStream_t stream) {
    const float* x = (const float*)d_in[0];
    // 256 independent blocks (1 per CU, 4 waves each); no workspace needed.
    ca_pipe<<<B * QBLKS, 256, 0, stream>>>(x, (v4i*)d_out);
}